// Round 11
// baseline (268.316 us; speedup 1.0000x reference)
//
#include <hip/hip_runtime.h>
#include <hip/hip_bf16.h>

#define H_DIM 512
#define N_HEADS 8
#define HEAD_DIM 64
#define NBATCH 16

typedef __attribute__((ext_vector_type(8))) short short8;   // 8 bf16 (4 VGPRs)
typedef __attribute__((ext_vector_type(4))) float floatx4;  // MFMA acc

typedef unsigned short us16;

// 3-bit row swizzle for XOR'd LDS slots (structurally conflict-free b128)
#define SW3(r) ((((r) >> 1) & 3) | (((r) & 1) << 2))

__device__ inline unsigned short f2bf(float f) {
  unsigned int u = __float_as_uint(f);
  unsigned int r = (u + 0x7fffu + ((u >> 16) & 1u)) >> 16;  // RNE
  return (unsigned short)r;
}

// async global->LDS, 16B/lane; lds dest = wave-uniform base + lane*16
__device__ inline void gld16(const us16* g, us16* l) {
  __builtin_amdgcn_global_load_lds(
      (const __attribute__((address_space(1))) void*)g,
      (__attribute__((address_space(3))) void*)l, 16, 0, 0);
}

// ---------------------------------------------------------------------------
// prep_all: one dispatch for (a) all fp32->bf16 casts + BN-stat zero
// [blocks 0..2047], (b) Wc = W1b @ Wm weight composite [blocks 2048..2111],
// (c) b1p = b1 + W1b @ bm [blocks 2112..2113]. All three are independent.
// ---------------------------------------------------------------------------
__global__ __launch_bounds__(256) void prep_all(
    const float* __restrict__ src_h, const float* __restrict__ dst_h,
    const float* __restrict__ Wq, const float* __restrict__ Wk,
    const float* __restrict__ Wv, const float* __restrict__ W1,
    const float* __restrict__ W2, const float* __restrict__ Wm,
    const float* __restrict__ b1, const float* __restrict__ bm,
    us16* __restrict__ src_bf, us16* __restrict__ dst_bf,
    us16* __restrict__ Wqb, us16* __restrict__ Wkv, us16* __restrict__ Wf,
    us16* __restrict__ W2b, float* __restrict__ b1p, float* __restrict__ st,
    int n_src, int n_dst) {
  __shared__ __align__(16) us16 As[64 * 48];
  __shared__ __align__(16) us16 Bs[64 * 48];
  const int blk = blockIdx.x;
  const int t = threadIdx.x;

  if (blk < 2048) {  // ---- casts ----
    if (blk == 0) {
      float4 z = make_float4(0.f, 0.f, 0.f, 0.f);
      ((float4*)st)[t] = z;
      ((float4*)st)[t + 256] = z;
    }
    const float* srcs[7] = {src_h, dst_h, Wq, Wk, Wv, W1, W2};
    us16* dsts[7] = {src_bf, dst_bf, Wqb, Wkv, Wkv + 262144, Wf, W2b};
    int ns[7] = {n_src, n_dst, 262144, 262144, 262144, 262144, 262144};
    for (int rg = 0; rg < 7; ++rg) {
      const float* sp = srcs[rg];
      us16* dp = dsts[rg];
      const bool strided = (rg == 5);  // W1a -> Wf cols 0:512 of 1024-wide rows
      for (int i = (blk * 256 + t) * 4; i < ns[rg]; i += 2048 * 256 * 4) {
        int j = strided ? ((i >> 9) * 1024 + (i & 511)) : i;
        float4 v = *(const float4*)(sp + j);
        ushort4 o;
        o.x = f2bf(v.x); o.y = f2bf(v.y); o.z = f2bf(v.z); o.w = f2bf(v.w);
        *(ushort4*)(dp + j) = o;
      }
    }
  } else if (blk < 2112) {  // ---- wprep: Wc[n][k] into Wf[n*1024+512+k] ----
    const int bx = (blk - 2048) & 7, byk = (blk - 2048) >> 3;
    const int w = t >> 6, lane = t & 63;
    const int lane15 = lane & 15, quad = lane >> 4;
    const int wm = w >> 1, wn = w & 1;
    const int bn_ = bx * 64, bk = byk * 64;
    floatx4 acc[2][2];
#pragma unroll
    for (int a = 0; a < 2; ++a)
#pragma unroll
      for (int c = 0; c < 2; ++c) acc[a][c] = (floatx4){0.f, 0.f, 0.f, 0.f};
    for (int j0 = 0; j0 < 512; j0 += 32) {
      {
        int n = t >> 2, jj0 = (t & 3) * 8;
        const float* rp = W1 + (size_t)(bn_ + n) * 1024 + 512 + j0 + jj0;
        float4 va = *(const float4*)(rp);
        float4 vb = *(const float4*)(rp + 4);
        ushort4 pa, pb;
        pa.x = f2bf(va.x); pa.y = f2bf(va.y); pa.z = f2bf(va.z); pa.w = f2bf(va.w);
        pb.x = f2bf(vb.x); pb.y = f2bf(vb.y); pb.z = f2bf(vb.z); pb.w = f2bf(vb.w);
        *(ushort4*)(As + n * 48 + jj0) = pa;
        *(ushort4*)(As + n * 48 + jj0 + 4) = pb;
      }
      {
        int jj = t >> 3, kc0 = (t & 7) * 8;
        const float* rp = Wm + (size_t)(j0 + jj) * 512 + bk + kc0;
        float4 va = *(const float4*)(rp);
        float4 vb = *(const float4*)(rp + 4);
        float vv[8] = {va.x, va.y, va.z, va.w, vb.x, vb.y, vb.z, vb.w};
#pragma unroll
        for (int e = 0; e < 8; ++e) Bs[(kc0 + e) * 48 + jj] = f2bf(vv[e]);
      }
      __syncthreads();
      short8 a_[2], b_[2];
#pragma unroll
      for (int mt = 0; mt < 2; ++mt)
        a_[mt] = *(const short8*)(As + (wm * 32 + mt * 16 + lane15) * 48 + quad * 8);
#pragma unroll
      for (int nt = 0; nt < 2; ++nt)
        b_[nt] = *(const short8*)(Bs + (wn * 32 + nt * 16 + lane15) * 48 + quad * 8);
#pragma unroll
      for (int mt = 0; mt < 2; ++mt)
#pragma unroll
        for (int nt = 0; nt < 2; ++nt)
          acc[mt][nt] = __builtin_amdgcn_mfma_f32_16x16x32_bf16(
              a_[mt], b_[nt], acc[mt][nt], 0, 0, 0);
      __syncthreads();
    }
#pragma unroll
    for (int mt = 0; mt < 2; ++mt) {
      int n0 = bn_ + wm * 32 + mt * 16 + quad * 4;
#pragma unroll
      for (int nt = 0; nt < 2; ++nt) {
        int k = bk + wn * 32 + nt * 16 + lane15;
#pragma unroll
        for (int r = 0; r < 4; ++r)
          Wf[(size_t)(n0 + r) * 1024 + 512 + k] = f2bf(acc[mt][nt][r]);
      }
    }
  } else {  // ---- b1prep ----
    int n = (blk - 2112) * 256 + t;
    if (n < 512) {
      const float* rp = W1 + (size_t)n * 1024 + 512;
      float s = 0.f;
      for (int j = 0; j < 512; j += 4) {
        float4 a = *(const float4*)(rp + j);
        float4 c = *(const float4*)(bm + j);
        s += a.x * c.x + a.y * c.y + a.z * c.z + a.w * c.w;
      }
      b1p[n] = b1[n] + s;
    }
  }
}

// ---------------------------------------------------------------------------
// 128x128 MFMA GEMM body (NT), BK=64, SINGLE buffer (32 KB LDS): 256 thr /
// 4 waves; wave w owns col strip w*32 over all 128 rows: 8 m-frags x 2
// n-frags = 32 MFMA + 20 ds_read_b128 + 8 gld16 per K-step. Latency hiding
// comes from 4 co-resident blocks/CU (launch_bounds cap), not from dbuf
// (dbuf measured neutral: compute phase << load latency).
// A row stride fixed 512; k0>=512 reads A2 (concat). N%128==0, K%64==0,
// M ragged-ok (loads clamped, stores guarded). W row stride = K.
// modes: 0 fp32 out + fused BN stats; 1 bf16 head planes; 4 KV fused.
// ---------------------------------------------------------------------------
__device__ inline void gemm_body(
    const us16* __restrict__ A1, const us16* __restrict__ A2,
    const us16* __restrict__ W,
    const float* __restrict__ bias0, const float* __restrict__ bias1,
    void* __restrict__ C0, void* __restrict__ C1, float* __restrict__ stats,
    int M, int N, int K, int mode, int bx, int by) {
  __shared__ __align__(16) us16 As[128 * 64];   // 16 KB
  __shared__ __align__(16) us16 Bs[128 * 64];   // 16 KB
  const int t = threadIdx.x, w = t >> 6, lane = t & 63;
  const int lane15 = lane & 15, quad = lane >> 4;
  const int bm = bx * 128, bn = by * 128;
  const int lrow = lane >> 3, sl = lane & 7;

  floatx4 acc[8][2];
#pragma unroll
  for (int a = 0; a < 8; ++a)
#pragma unroll
    for (int c = 0; c < 2; ++c) acc[a][c] = (floatx4){0.f, 0.f, 0.f, 0.f};

  for (int k0 = 0; k0 < K; k0 += 64) {
    const us16* Ab = (k0 < 512) ? A1 : A2;
    const int ka = k0 & 511;
    // stage A[128x64] + B[128x64]; wave w rows [w*32, w*32+32)
#pragma unroll
    for (int p = 0; p < 4; ++p) {
      int rbase = w * 32 + p * 8;
      int row = rbase + lrow;
      int kg = sl ^ SW3(row);
      int gr = bm + row; gr = (gr < M) ? gr : (M - 1);
      gld16(Ab + (size_t)gr * 512 + ka + kg * 8, As + rbase * 64);
      gld16(W + (size_t)(bn + row) * K + k0 + kg * 8, Bs + rbase * 64);
    }
    __syncthreads();
#pragma unroll
    for (int kh = 0; kh < 2; ++kh) {
      const int g = kh * 4 + quad;
      short8 b0, b1v;
      {
        int c0 = w * 32 + lane15;
        int c1 = c0 + 16;
        b0 = *(const short8*)(Bs + c0 * 64 + (g ^ SW3(c0)) * 8);
        b1v = *(const short8*)(Bs + c1 * 64 + (g ^ SW3(c1)) * 8);
      }
#pragma unroll
      for (int mt = 0; mt < 8; ++mt) {
        int r = mt * 16 + lane15;
        short8 a_ = *(const short8*)(As + r * 64 + (g ^ SW3(r)) * 8);
        acc[mt][0] = __builtin_amdgcn_mfma_f32_16x16x32_bf16(a_, b0, acc[mt][0], 0, 0, 0);
        acc[mt][1] = __builtin_amdgcn_mfma_f32_16x16x32_bf16(a_, b1v, acc[mt][1], 0, 0, 0);
      }
    }
    __syncthreads();
  }

  if (mode == 0) {
#pragma unroll
    for (int nt = 0; nt < 2; ++nt) {
      int col = bn + w * 32 + nt * 16 + lane15;
      float bv = bias0[col];
      float s = 0.f, qq = 0.f;
#pragma unroll
      for (int mt = 0; mt < 8; ++mt) {
        int row0 = bm + mt * 16 + quad * 4;
        if (row0 < M) {
#pragma unroll
          for (int r = 0; r < 4; ++r) {
            float val = acc[mt][nt][r] + bv;
            ((float*)C0)[(size_t)(row0 + r) * N + col] = val;
            s += val; qq = fmaf(val, val, qq);
          }
        }
      }
      s += __shfl_xor(s, 16); s += __shfl_xor(s, 32);
      qq += __shfl_xor(qq, 16); qq += __shfl_xor(qq, 32);
      if (quad == 0) {
        atomicAdd(&stats[col], s);
        atomicAdd(&stats[512 + col], qq);
      }
    }
  } else if (mode == 1) {
#pragma unroll
    for (int nt = 0; nt < 2; ++nt) {
      int col = bn + w * 32 + nt * 16 + lane15;
      float bv = bias0[col];
      int hh = col & 7, dd = col >> 3;
#pragma unroll
      for (int mt = 0; mt < 8; ++mt) {
        int row0 = bm + mt * 16 + quad * 4;
        if (row0 < M) {
#pragma unroll
          for (int r = 0; r < 4; ++r)
            ((us16*)C0)[((size_t)hh * M + row0 + r) * 64 + dd] = f2bf(acc[mt][nt][r] + bv);
        }
      }
    }
  } else {  // mode 4: KV fused (N=1024)
#pragma unroll
    for (int nt = 0; nt < 2; ++nt) {
      int col = bn + w * 32 + nt * 16 + lane15;
      if (col < 512) {
        float bv = bias0[col];
        int hh = col & 7, dd = col >> 3;
#pragma unroll
        for (int mt = 0; mt < 8; ++mt) {
          int row0 = bm + mt * 16 + quad * 4;
          if (row0 < M) {
#pragma unroll
            for (int r = 0; r < 4; ++r)
              ((us16*)C0)[((size_t)hh * M + row0 + r) * 64 + dd] = f2bf(acc[mt][nt][r] + bv);
          }
        }
      } else {
        int cv = col - 512;
        float bv = bias1[cv];
        int plane = (cv & 7) * 64 + (cv >> 3);
#pragma unroll
        for (int mt = 0; mt < 8; ++mt) {
          int row0 = bm + mt * 16 + quad * 4;
          if (row0 < M) {
            ushort4 pk;
            pk.x = f2bf(acc[mt][nt][0] + bv);
            pk.y = f2bf(acc[mt][nt][1] + bv);
            pk.z = f2bf(acc[mt][nt][2] + bv);
            pk.w = f2bf(acc[mt][nt][3] + bv);
            *(ushort4*)((us16*)C1 + (size_t)plane * M + row0) = pk;
          }
        }
      }
    }
  }
}

// FFN GEMM: XCD-aware 1D grid (nM=47 mtiles, 4 ntiles, grid 192).
// Siblings of an A-panel share id%8 -> same XCD -> panel fetched once.
__global__ __launch_bounds__(256, 4) void gemm_ffn(
    const us16* __restrict__ A1, const us16* __restrict__ A2,
    const us16* __restrict__ W,
    const float* __restrict__ bias0, void* __restrict__ C0,
    float* __restrict__ stats, int M, int K) {
  int x = blockIdx.x & 7, j = blockIdx.x >> 3;
  int sib = j & 3, pl = j >> 2;
  int panel = pl * 8 + x;
  if (panel * 128 >= M) return;
  gemm_body(A1, A2, W, bias0, nullptr, C0, nullptr, stats, M, 512, K, 0,
            panel, sib);
}

// Q (ids 0..191: 47 panels x 4 sibs) + KV (ids 192..703: 57 panels x 8 sibs),
// both sections XCD-striped (192 % 8 == 0 preserves id%8 identity).
__global__ __launch_bounds__(256, 4) void gemm_qkv(
    const us16* __restrict__ dst_bf, const us16* __restrict__ src_bf,
    const us16* __restrict__ Wqb, const us16* __restrict__ Wkv,
    const float* __restrict__ bq, const float* __restrict__ bk,
    const float* __restrict__ bv,
    us16* __restrict__ Qh, us16* __restrict__ Kh, us16* __restrict__ Vt,
    int Md, int Ms) {
  int id = blockIdx.x;
  if (id < 192) {
    int x = id & 7, j = id >> 3;
    int sib = j & 3, pl = j >> 2;
    int panel = pl * 8 + x;
    if (panel * 128 >= Md) return;
    gemm_body(dst_bf, dst_bf, Wqb, bq, nullptr, Qh, nullptr, nullptr,
              Md, 512, 512, 1, panel, sib);
  } else {
    int id2 = id - 192;
    int x = id2 & 7, j = id2 >> 3;
    int sib = j & 7, pl = j >> 3;
    int panel = pl * 8 + x;
    if (panel * 128 >= Ms) return;
    gemm_body(src_bf, src_bf, Wkv, bk, bv, Kh, Vt, nullptr,
              Ms, 1024, 512, 4, panel, sib);
  }
}

// ---------------------------------------------------------------------------
// attn_v6 (unchanged): 4 waves x 16 dst rows of one (b,h); K/Vt chunks
// staged via global_load_lds (SW3 swizzle); per-wave register softmax;
// 2 barriers per chunk. Grid (16, 8, 8), 256 thr.
// ---------------------------------------------------------------------------
__global__ __launch_bounds__(256) void attn_v6(
    const us16* __restrict__ Qh, const us16* __restrict__ Kh,
    const us16* __restrict__ Vt, const int* __restrict__ dlens,
    const int* __restrict__ slens, us16* __restrict__ O,
    int Md, int Ms) {
  const int b = blockIdx.x, h = blockIdx.y, tile = blockIdx.z;
  int doff = 0, soff = 0;
  for (int i = 0; i < NBATCH; ++i)
    if (i < b) { doff += dlens[i]; soff += slens[i]; }
  const int dlen = dlens[b], slen = slens[b];
  if (tile * 64 >= dlen) return;

  __shared__ __align__(16) us16 Ks[64 * 64];
  __shared__ __align__(16) us16 Vts[64 * 64];
  __shared__ __align__(16) us16 Pw[4][16 * 72];

  const int t = threadIdx.x, wv = t >> 6, lane = t & 63;
  const int lane15 = lane & 15, quad = lane >> 4;
  const int i0w = tile * 64 + wv * 16;
  const bool active = i0w < dlen;  // dlen % 16 == 0

  const us16* Qp = Qh + ((size_t)h * Md + doff + (active ? i0w : 0)) * 64;
  const us16* Kp = Kh + ((size_t)h * Ms + soff) * 64;
  const us16* Vtp = Vt + ((size_t)h * 64) * Ms + soff;

  short8 af0 = *(const short8*)(Qp + (size_t)lane15 * 64 + quad * 8);
  short8 af1 = *(const short8*)(Qp + (size_t)lane15 * 64 + 32 + quad * 8);

  floatx4 oa[4];
#pragma unroll
  for (int nt = 0; nt < 4; ++nt) oa[nt] = (floatx4){0.f, 0.f, 0.f, 0.f};
  float m_r[4] = {-3.0e38f, -3.0e38f, -3.0e38f, -3.0e38f};
  float l_r[4] = {0.f, 0.f, 0.f, 0.f};

  for (int j0 = 0; j0 < slen; j0 += 64) {
#pragma unroll
    for (int p = 0; p < 2; ++p) {
      int row = wv * 16 + p * 8 + (lane >> 3);
      int sl = lane & 7;
      int kg = sl ^ SW3(row);
      gld16(Kp + (size_t)(j0 + row) * 64 + kg * 8, Ks + (wv * 16 + p * 8) * 64);
      gld16(Vtp + (size_t)row * Ms + j0 + kg * 8, Vts + (wv * 16 + p * 8) * 64);
    }
    __syncthreads();

    if (active) {
      floatx4 s[4];
#pragma unroll
      for (int jt = 0; jt < 4; ++jt) {
        int j = jt * 16 + lane15;
        short8 b0 = *(const short8*)(Ks + j * 64 + ((quad ^ SW3(j)) * 8));
        short8 b1 = *(const short8*)(Ks + j * 64 + (((4 + quad) ^ SW3(j)) * 8));
        floatx4 a = (floatx4){0.f, 0.f, 0.f, 0.f};
        a = __builtin_amdgcn_mfma_f32_16x16x32_bf16(af0, b0, a, 0, 0, 0);
        a = __builtin_amdgcn_mfma_f32_16x16x32_bf16(af1, b1, a, 0, 0, 0);
        s[jt] = a;
      }
      float mx[4] = {-3.0e38f, -3.0e38f, -3.0e38f, -3.0e38f};
#pragma unroll
      for (int jt = 0; jt < 4; ++jt) {
        bool valid = (j0 + jt * 16 + lane15) < slen;
#pragma unroll
        for (int r = 0; r < 4; ++r) {
          float v = valid ? s[jt][r] * 0.125f : -3.0e38f;
          s[jt][r] = v;
          mx[r] = fmaxf(mx[r], v);
        }
      }
#pragma unroll
      for (int r = 0; r < 4; ++r) {
        mx[r] = fmaxf(mx[r], __shfl_xor(mx[r], 1));
        mx[r] = fmaxf(mx[r], __shfl_xor(mx[r], 2));
        mx[r] = fmaxf(mx[r], __shfl_xor(mx[r], 4));
        mx[r] = fmaxf(mx[r], __shfl_xor(mx[r], 8));
      }
      float al[4], sum[4];
#pragma unroll
      for (int r = 0; r < 4; ++r) {
        float mn = fmaxf(m_r[r], mx[r]);
        al[r] = __expf(m_r[r] - mn);
        m_r[r] = mn;
        sum[r] = 0.f;
      }
#pragma unroll
      for (int jt = 0; jt < 4; ++jt)
#pragma unroll
        for (int r = 0; r < 4; ++r) {
          float e = __expf(s[jt][r] - m_r[r]);
          sum[r] += e;
          Pw[wv][(quad * 4 + r) * 72 + jt * 16 + lane15] = f2bf(e);
        }
#pragma unroll
      for (int r = 0; r < 4; ++r) {
        sum[r] += __shfl_xor(sum[r], 1);
        sum[r] += __shfl_xor(sum[r], 2);
        sum[r] += __shfl_xor(sum[r], 4);
        sum[r] += __shfl_xor(sum[r], 8);
        l_r[r] = l_r[r] * al[r] + sum[r];
      }
#pragma unroll
      for (int nt = 0; nt < 4; ++nt)
#pragma unroll
        for (int r = 0; r < 4; ++r) oa[nt][r] *= al[r];
      short8 pa0 = *(const short8*)(&Pw[wv][lane15 * 72 + quad * 8]);
      short8 pa1 = *(const short8*)(&Pw[wv][lane15 * 72 + 32 + quad * 8]);
#pragma unroll
      for (int nt = 0; nt < 4; ++nt) {
        int d = nt * 16 + lane15;
        short8 v0 = *(const short8*)(Vts + d * 64 + ((quad ^ SW3(d)) * 8));
        short8 v1 = *(const short8*)(Vts + d * 64 + (((4 + quad) ^ SW3(d)) * 8));
        oa[nt] = __builtin_amdgcn_mfma_f32_16x16x32_bf16(pa0, v0, oa[nt], 0, 0, 0);
        oa[nt] = __builtin_amdgcn_mfma_f32_16x16x32_bf16(pa1, v1, oa[nt], 0, 0, 0);
      }
    }
    __syncthreads();
  }

  if (active) {
    float linv[4];
#pragma unroll
    for (int r = 0; r < 4; ++r) linv[r] = 1.f / l_r[r];
#pragma unroll
    for (int r = 0; r < 4; ++r) {
      int i = quad * 4 + r;
      us16* orow = O + (size_t)(doff + i0w + i) * H_DIM + h;
#pragma unroll
      for (int nt = 0; nt < 4; ++nt) {
        int d = nt * 16 + lane15;
        orow[d * 8] = f2bf(oa[nt][r] * linv[r]);
      }
    }
  }
}

// ---------------------------------------------------------------------------
// BN apply: optional ReLU / residual; out_bf selects bf16 vs fp32 output.
// ---------------------------------------------------------------------------
__global__ __launch_bounds__(256) void bn_apply(
    const float* __restrict__ X, const float* __restrict__ stats,
    const float* __restrict__ g, const float* __restrict__ be,
    const float* __restrict__ resid, void* __restrict__ Y,
    int M, float invM, int relu, int out_bf) {
  const size_t total = (size_t)M * H_DIM;
  for (size_t i = (size_t)blockIdx.x * 256 + threadIdx.x; i < total;
       i += (size_t)gridDim.x * 256) {
    int c = (int)(i & (H_DIM - 1));
    float mean = stats[c] * invM;
    float var = fmaf(-mean, mean, stats[H_DIM + c] * invM);
    float x = X[i];
    float y = (x - mean) * rsqrtf(var + 1e-5f) * g[c] + be[c];
    if (relu) y = fmaxf(y, 0.f);
    if (resid) y += resid[i];
    if (out_bf) ((us16*)Y)[i] = f2bf(y);
    else ((float*)Y)[i] = y;
  }
}

// ---------------------------------------------------------------------------
extern "C" void kernel_launch(void* const* d_in, const int* in_sizes, int n_in,
                              void* d_out, int out_size, void* d_ws, size_t ws_size,
                              hipStream_t stream) {
  const float* src_h = (const float*)d_in[0];
  const float* dst_h = (const float*)d_in[1];
  const int* s_lens  = (const int*)d_in[2];
  const int* d_lens  = (const int*)d_in[3];
  const float* Wq = (const float*)d_in[4];  const float* bq = (const float*)d_in[5];
  const float* Wk = (const float*)d_in[6];  const float* bk = (const float*)d_in[7];
  const float* Wv = (const float*)d_in[8];  const float* bv = (const float*)d_in[9];
  const float* Wm = (const float*)d_in[10]; const float* bm = (const float*)d_in[11];
  const float* W1 = (const float*)d_in[12]; const float* b1 = (const float*)d_in[13];
  const float* g1 = (const float*)d_in[14]; const float* be1 = (const float*)d_in[15];
  const float* W2 = (const float*)d_in[16]; const float* b2 = (const float*)d_in[17];
  const float* g2 = (const float*)d_in[18]; const float* be2 = (const float*)d_in[19];

  const int total_src = in_sizes[0] / H_DIM;  // 7232
  const int total_dst = in_sizes[1] / H_DIM;  // 6016 = 47*128

  // ---- workspace layout (byte offsets); peak ~50.5 MB ----
  char* ws = (char*)d_ws;
  us16* src_bf = (us16*)(ws + 0);                    //  7,405,568
  us16* dst_bf = (us16*)(ws + 7405568);              //  6,160,384
  us16* wbf    = (us16*)(ws + 13565952);             //  3,145,728 used
  float* b1p   = (float*)(ws + 16711680);            //  2,048
  us16* Qh     = (us16*)(ws + 17235968);             //  6,160,384
  us16* Kh     = (us16*)(ws + 23396352);             //  7,405,568
  us16* Vt     = (us16*)(ws + 30801920);             //  7,405,568
  us16* Ob     = (us16*)(ws + 38207488);             //  6,160,384
  us16* X1bf   = (us16*)(ws + 44367872);             //  6,160,384
  float* st    = (float*)(ws + 50528256);            //  8,192
  float* X1    = (float*)(ws + 17235968);            // aliases Qh+Kh (dead)
  float* X2    = (float*)(ws + 30801920);            // aliases Vt+Ob (dead)
  float* st1 = st, *st2 = st + 1024;

  us16* Wqb = wbf;                 // 262144 elems
  us16* Wkv = wbf + 262144;        // 524288 (Wk rows then Wv rows)
  us16* Wf  = wbf + 786432;        // 524288 ([W1a | Wc] rows of 1024)
  us16* W2b = wbf + 1310720;       // 262144

  const dim3 blk256(256);

  // 1: casts + weight composites + BN-stat zero
  prep_all<<<dim3(2114), blk256, 0, stream>>>(
      src_h, dst_h, Wq, Wk, Wv, W1, W2, Wm, b1, bm,
      src_bf, dst_bf, Wqb, Wkv, Wf, W2b, b1p, st,
      total_src * H_DIM, total_dst * H_DIM);

  // 2: Q + fused K/V projections (XCD-striped 1D grid: 192 + 512 = 704)
  gemm_qkv<<<dim3(704), blk256, 0, stream>>>(
      dst_bf, src_bf, Wqb, Wkv, bq, bk, bv, Qh, Kh, Vt, total_dst, total_src);

  // 3: attention -> Ob (bf16 [M,512])
  attn_v6<<<dim3(NBATCH, N_HEADS, 8), blk256, 0, stream>>>(
      Qh, Kh, Vt, d_lens, s_lens, Ob, total_dst, total_src);

  // 4: FFN1 (merge folded in): [dst_bf | Ob] @ Wf^T + b1p -> X1 + BN1 stats
  gemm_ffn<<<dim3(192), blk256, 0, stream>>>(
      dst_bf, Ob, Wf, b1p, X1, st1, total_dst, 1024);

  // 5: BN1 + ReLU -> X1bf
  bn_apply<<<dim3(512), blk256, 0, stream>>>(X1, st1, g1, be1, nullptr, X1bf,
                                             total_dst, 1.f / (float)total_dst, 1, 1);

  // 6: FFN2 -> X2 + BN2 stats
  gemm_ffn<<<dim3(192), blk256, 0, stream>>>(
      X1bf, X1bf, W2b, b2, X2, st2, total_dst, 512);

  // 7: BN2 + residual -> d_out
  bn_apply<<<dim3(512), blk256, 0, stream>>>(X2, st2, g2, be2, dst_h, d_out,
                                             total_dst, 1.f / (float)total_dst, 0, 0);
}

// Round 12
// 258.351 us; speedup vs baseline: 1.0386x; 1.0386x over previous
//
#include <hip/hip_runtime.h>
#include <hip/hip_bf16.h>

#define H_DIM 512
#define N_HEADS 8
#define HEAD_DIM 64
#define NBATCH 16

typedef __attribute__((ext_vector_type(8))) short short8;   // 8 bf16 (4 VGPRs)
typedef __attribute__((ext_vector_type(4))) float floatx4;  // MFMA acc

typedef unsigned short us16;

// 3-bit row swizzle for XOR'd LDS slots (structurally conflict-free b128)
#define SW3(r) ((((r) >> 1) & 3) | (((r) & 1) << 2))

__device__ inline unsigned short f2bf(float f) {
  unsigned int u = __float_as_uint(f);
  unsigned int r = (u + 0x7fffu + ((u >> 16) & 1u)) >> 16;  // RNE
  return (unsigned short)r;
}

// async global->LDS, 16B/lane; lds dest = wave-uniform base + lane*16
__device__ inline void gld16(const us16* g, us16* l) {
  __builtin_amdgcn_global_load_lds(
      (const __attribute__((address_space(1))) void*)g,
      (__attribute__((address_space(3))) void*)l, 16, 0, 0);
}

// ---------------------------------------------------------------------------
// prep_all: one dispatch for (a) all fp32->bf16 casts + BN-stat zero
// [blocks 0..2047], (b) Wc = W1b @ Wm weight composite [blocks 2048..2111],
// (c) b1p = b1 + W1b @ bm [blocks 2112..2113]. All three are independent.
// ---------------------------------------------------------------------------
__global__ __launch_bounds__(256) void prep_all(
    const float* __restrict__ src_h, const float* __restrict__ dst_h,
    const float* __restrict__ Wq, const float* __restrict__ Wk,
    const float* __restrict__ Wv, const float* __restrict__ W1,
    const float* __restrict__ W2, const float* __restrict__ Wm,
    const float* __restrict__ b1, const float* __restrict__ bm,
    us16* __restrict__ src_bf, us16* __restrict__ dst_bf,
    us16* __restrict__ Wqb, us16* __restrict__ Wkv, us16* __restrict__ Wf,
    us16* __restrict__ W2b, float* __restrict__ b1p, float* __restrict__ st,
    int n_src, int n_dst) {
  __shared__ __align__(16) us16 As[64 * 48];
  __shared__ __align__(16) us16 Bs[64 * 48];
  const int blk = blockIdx.x;
  const int t = threadIdx.x;

  if (blk < 2048) {  // ---- casts ----
    if (blk == 0) {
      float4 z = make_float4(0.f, 0.f, 0.f, 0.f);
      ((float4*)st)[t] = z;
      ((float4*)st)[t + 256] = z;
    }
    const float* srcs[7] = {src_h, dst_h, Wq, Wk, Wv, W1, W2};
    us16* dsts[7] = {src_bf, dst_bf, Wqb, Wkv, Wkv + 262144, Wf, W2b};
    int ns[7] = {n_src, n_dst, 262144, 262144, 262144, 262144, 262144};
    for (int rg = 0; rg < 7; ++rg) {
      const float* sp = srcs[rg];
      us16* dp = dsts[rg];
      const bool strided = (rg == 5);  // W1a -> Wf cols 0:512 of 1024-wide rows
      for (int i = (blk * 256 + t) * 4; i < ns[rg]; i += 2048 * 256 * 4) {
        int j = strided ? ((i >> 9) * 1024 + (i & 511)) : i;
        float4 v = *(const float4*)(sp + j);
        ushort4 o;
        o.x = f2bf(v.x); o.y = f2bf(v.y); o.z = f2bf(v.z); o.w = f2bf(v.w);
        *(ushort4*)(dp + j) = o;
      }
    }
  } else if (blk < 2112) {  // ---- wprep: Wc[n][k] into Wf[n*1024+512+k] ----
    const int bx = (blk - 2048) & 7, byk = (blk - 2048) >> 3;
    const int w = t >> 6, lane = t & 63;
    const int lane15 = lane & 15, quad = lane >> 4;
    const int wm = w >> 1, wn = w & 1;
    const int bn_ = bx * 64, bk = byk * 64;
    floatx4 acc[2][2];
#pragma unroll
    for (int a = 0; a < 2; ++a)
#pragma unroll
      for (int c = 0; c < 2; ++c) acc[a][c] = (floatx4){0.f, 0.f, 0.f, 0.f};
    for (int j0 = 0; j0 < 512; j0 += 32) {
      {
        int n = t >> 2, jj0 = (t & 3) * 8;
        const float* rp = W1 + (size_t)(bn_ + n) * 1024 + 512 + j0 + jj0;
        float4 va = *(const float4*)(rp);
        float4 vb = *(const float4*)(rp + 4);
        ushort4 pa, pb;
        pa.x = f2bf(va.x); pa.y = f2bf(va.y); pa.z = f2bf(va.z); pa.w = f2bf(va.w);
        pb.x = f2bf(vb.x); pb.y = f2bf(vb.y); pb.z = f2bf(vb.z); pb.w = f2bf(vb.w);
        *(ushort4*)(As + n * 48 + jj0) = pa;
        *(ushort4*)(As + n * 48 + jj0 + 4) = pb;
      }
      {
        int jj = t >> 3, kc0 = (t & 7) * 8;
        const float* rp = Wm + (size_t)(j0 + jj) * 512 + bk + kc0;
        float4 va = *(const float4*)(rp);
        float4 vb = *(const float4*)(rp + 4);
        float vv[8] = {va.x, va.y, va.z, va.w, vb.x, vb.y, vb.z, vb.w};
#pragma unroll
        for (int e = 0; e < 8; ++e) Bs[(kc0 + e) * 48 + jj] = f2bf(vv[e]);
      }
      __syncthreads();
      short8 a_[2], b_[2];
#pragma unroll
      for (int mt = 0; mt < 2; ++mt)
        a_[mt] = *(const short8*)(As + (wm * 32 + mt * 16 + lane15) * 48 + quad * 8);
#pragma unroll
      for (int nt = 0; nt < 2; ++nt)
        b_[nt] = *(const short8*)(Bs + (wn * 32 + nt * 16 + lane15) * 48 + quad * 8);
#pragma unroll
      for (int mt = 0; mt < 2; ++mt)
#pragma unroll
        for (int nt = 0; nt < 2; ++nt)
          acc[mt][nt] = __builtin_amdgcn_mfma_f32_16x16x32_bf16(
              a_[mt], b_[nt], acc[mt][nt], 0, 0, 0);
      __syncthreads();
    }
#pragma unroll
    for (int mt = 0; mt < 2; ++mt) {
      int n0 = bn_ + wm * 32 + mt * 16 + quad * 4;
#pragma unroll
      for (int nt = 0; nt < 2; ++nt) {
        int k = bk + wn * 32 + nt * 16 + lane15;
#pragma unroll
        for (int r = 0; r < 4; ++r)
          Wf[(size_t)(n0 + r) * 1024 + 512 + k] = f2bf(acc[mt][nt][r]);
      }
    }
  } else {  // ---- b1prep ----
    int n = (blk - 2112) * 256 + t;
    if (n < 512) {
      const float* rp = W1 + (size_t)n * 1024 + 512;
      float s = 0.f;
      for (int j = 0; j < 512; j += 4) {
        float4 a = *(const float4*)(rp + j);
        float4 c = *(const float4*)(bm + j);
        s += a.x * c.x + a.y * c.y + a.z * c.z + a.w * c.w;
      }
      b1p[n] = b1[n] + s;
    }
  }
}

// ---------------------------------------------------------------------------
// 128x128 MFMA GEMM body (NT), BK=64, single buffer. 256 thr / 4 waves;
// wave w owns col strip w*32 over all 128 rows (8 m-frags x 2 n-frags =
// 32 MFMA per K-step per wave). global_load_lds + SW3 swizzle staging.
// Epilogue for bf16 plane outputs (modes 1/4) routes the C tile through
// LDS (Cs, pitch 142) and emits coalesced 16B stores:
//   head planes -> 32B row-runs (sibling by-blocks on same XCD merge lines)
//   Vt planes   -> 128B contiguous column runs (100% line utilization)
// mode 0 keeps direct coalesced fp32 stores + fused BN stats.
// A row stride fixed 512; k0>=512 reads A2 (concat). N%128==0, K%64==0,
// M ragged-ok (loads clamped, stores guarded). W row stride = K.
// ---------------------------------------------------------------------------
#define CSP 142  // Cs pitch in elems (284B rows -> <=2-way banks both phases)

__device__ inline void gemm_body(
    const us16* __restrict__ A1, const us16* __restrict__ A2,
    const us16* __restrict__ W,
    const float* __restrict__ bias0, const float* __restrict__ bias1,
    void* __restrict__ C0, void* __restrict__ C1, float* __restrict__ stats,
    int M, int N, int K, int mode, int bx, int by) {
  __shared__ __align__(16) us16 shbuf[128 * CSP];  // 36352 B
  us16* As = shbuf;          // 128x64 staging (16 KB)
  us16* Bs = shbuf + 8192;   // 128x64 staging (16 KB)
  const int t = threadIdx.x, w = t >> 6, lane = t & 63;
  const int lane15 = lane & 15, quad = lane >> 4;
  const int bm = bx * 128, bn = by * 128;
  const int lrow = lane >> 3, sl = lane & 7;

  floatx4 acc[8][2];
#pragma unroll
  for (int a = 0; a < 8; ++a)
#pragma unroll
    for (int c = 0; c < 2; ++c) acc[a][c] = (floatx4){0.f, 0.f, 0.f, 0.f};

  for (int k0 = 0; k0 < K; k0 += 64) {
    const us16* Ab = (k0 < 512) ? A1 : A2;
    const int ka = k0 & 511;
#pragma unroll
    for (int p = 0; p < 4; ++p) {
      int rbase = w * 32 + p * 8;
      int row = rbase + lrow;
      int kg = sl ^ SW3(row);
      int gr = bm + row; gr = (gr < M) ? gr : (M - 1);
      gld16(Ab + (size_t)gr * 512 + ka + kg * 8, As + rbase * 64);
      gld16(W + (size_t)(bn + row) * K + k0 + kg * 8, Bs + rbase * 64);
    }
    __syncthreads();
#pragma unroll
    for (int kh = 0; kh < 2; ++kh) {
      const int g = kh * 4 + quad;
      short8 b0, b1v;
      {
        int c0 = w * 32 + lane15;
        int c1 = c0 + 16;
        b0 = *(const short8*)(Bs + c0 * 64 + (g ^ SW3(c0)) * 8);
        b1v = *(const short8*)(Bs + c1 * 64 + (g ^ SW3(c1)) * 8);
      }
#pragma unroll
      for (int mt = 0; mt < 8; ++mt) {
        int r = mt * 16 + lane15;
        short8 a_ = *(const short8*)(As + r * 64 + (g ^ SW3(r)) * 8);
        acc[mt][0] = __builtin_amdgcn_mfma_f32_16x16x32_bf16(a_, b0, acc[mt][0], 0, 0, 0);
        acc[mt][1] = __builtin_amdgcn_mfma_f32_16x16x32_bf16(a_, b1v, acc[mt][1], 0, 0, 0);
      }
    }
    __syncthreads();
  }

  if (mode == 0) {
#pragma unroll
    for (int nt = 0; nt < 2; ++nt) {
      int col = bn + w * 32 + nt * 16 + lane15;
      float bv = bias0[col];
      float s = 0.f, qq = 0.f;
#pragma unroll
      for (int mt = 0; mt < 8; ++mt) {
        int row0 = bm + mt * 16 + quad * 4;
        if (row0 < M) {
#pragma unroll
          for (int r = 0; r < 4; ++r) {
            float val = acc[mt][nt][r] + bv;
            ((float*)C0)[(size_t)(row0 + r) * N + col] = val;
            s += val; qq = fmaf(val, val, qq);
          }
        }
      }
      s += __shfl_xor(s, 16); s += __shfl_xor(s, 32);
      qq += __shfl_xor(qq, 16); qq += __shfl_xor(qq, 32);
      if (quad == 0) {
        atomicAdd(&stats[col], s);
        atomicAdd(&stats[512 + col], qq);
      }
    }
  } else {
    // ---- bf16 plane outputs: stage biased C tile into LDS, then coalesce --
    const bool vpart = (mode == 4) && (bn >= 512);
#pragma unroll
    for (int nt = 0; nt < 2; ++nt) {
      int colw = w * 32 + nt * 16 + lane15;
      float bv = vpart ? bias1[bn + colw - 512] : bias0[bn + colw];
#pragma unroll
      for (int mt = 0; mt < 8; ++mt) {
        int roww = mt * 16 + quad * 4;
#pragma unroll
        for (int r = 0; r < 4; ++r)
          shbuf[(roww + r) * CSP + colw] = f2bf(acc[mt][nt][r] + bv);
      }
    }
    __syncthreads();
    if (!vpart) {
      // head planes: (h, grow) row gets 16 dd entries = two 16B stores
#pragma unroll
      for (int p = 0; p < 4; ++p) {
        int idx = p * 256 + t;
        int row = idx & 127, h = idx >> 7;  // h = 2*p + (t>>7)
        int grow = bm + row;
        if (grow < M) {
          us16* op = (us16*)C0 + ((size_t)h * M + grow) * 64 + (bn >> 3);
#pragma unroll
          for (int half = 0; half < 2; ++half) {
            us16 tmp[8];
#pragma unroll
            for (int e = 0; e < 8; ++e)
              tmp[e] = shbuf[row * CSP + (half * 8 + e) * 8 + h];
            *(uint4*)(op + half * 8) = *(uint4*)tmp;
          }
        }
      }
    } else {
      // Vt planes: column c -> plane, 64-row contiguous run (8 x 16B stores)
      int c = t >> 1, halfsel = t & 1;
      int cv = bn + c - 512;
      int plane = (cv & 7) * 64 + (cv >> 3);
      int r0 = halfsel * 64;
      if (bm + r0 < M) {  // M % 64 == 0 -> whole 64-row run valid
        us16* op = (us16*)C1 + (size_t)plane * M + bm + r0;
#pragma unroll
        for (int qq = 0; qq < 8; ++qq) {
          us16 tmp[8];
#pragma unroll
          for (int e = 0; e < 8; ++e)
            tmp[e] = shbuf[(r0 + qq * 8 + e) * CSP + c];
          *(uint4*)(op + qq * 8) = *(uint4*)tmp;
        }
      }
    }
  }
}

// FFN GEMM: XCD-aware 1D grid (47 panels x 4 ntiles).
__global__ __launch_bounds__(256, 4) void gemm_ffn(
    const us16* __restrict__ A1, const us16* __restrict__ A2,
    const us16* __restrict__ W,
    const float* __restrict__ bias0, void* __restrict__ C0,
    float* __restrict__ stats, int M, int K) {
  int x = blockIdx.x & 7, j = blockIdx.x >> 3;
  int sib = j & 3, pl = j >> 2;
  int panel = pl * 8 + x;
  if (panel * 128 >= M) return;
  gemm_body(A1, A2, W, bias0, nullptr, C0, nullptr, stats, M, 512, K, 0,
            panel, sib);
}

// Q (ids 0..191) + KV (ids 192..703), XCD-striped (id%8 = XCD).
__global__ __launch_bounds__(256, 4) void gemm_qkv(
    const us16* __restrict__ dst_bf, const us16* __restrict__ src_bf,
    const us16* __restrict__ Wqb, const us16* __restrict__ Wkv,
    const float* __restrict__ bq, const float* __restrict__ bk,
    const float* __restrict__ bv,
    us16* __restrict__ Qh, us16* __restrict__ Kh, us16* __restrict__ Vt,
    int Md, int Ms) {
  int id = blockIdx.x;
  if (id < 192) {
    int x = id & 7, j = id >> 3;
    int sib = j & 3, pl = j >> 2;
    int panel = pl * 8 + x;
    if (panel * 128 >= Md) return;
    gemm_body(dst_bf, dst_bf, Wqb, bq, nullptr, Qh, nullptr, nullptr,
              Md, 512, 512, 1, panel, sib);
  } else {
    int id2 = id - 192;
    int x = id2 & 7, j = id2 >> 3;
    int sib = j & 7, pl = j >> 3;
    int panel = pl * 8 + x;
    if (panel * 128 >= Ms) return;
    gemm_body(src_bf, src_bf, Wkv, bk, bv, Kh, Vt, nullptr,
              Ms, 1024, 512, 4, panel, sib);
  }
}

// ---------------------------------------------------------------------------
// attn_v6 (unchanged): 4 waves x 16 dst rows of one (b,h); K/Vt chunks
// staged via global_load_lds (SW3 swizzle); per-wave register softmax;
// 2 barriers per chunk. Grid (16, 8, 8), 256 thr.
// ---------------------------------------------------------------------------
__global__ __launch_bounds__(256) void attn_v6(
    const us16* __restrict__ Qh, const us16* __restrict__ Kh,
    const us16* __restrict__ Vt, const int* __restrict__ dlens,
    const int* __restrict__ slens, us16* __restrict__ O,
    int Md, int Ms) {
  const int b = blockIdx.x, h = blockIdx.y, tile = blockIdx.z;
  int doff = 0, soff = 0;
  for (int i = 0; i < NBATCH; ++i)
    if (i < b) { doff += dlens[i]; soff += slens[i]; }
  const int dlen = dlens[b], slen = slens[b];
  if (tile * 64 >= dlen) return;

  __shared__ __align__(16) us16 Ks[64 * 64];
  __shared__ __align__(16) us16 Vts[64 * 64];
  __shared__ __align__(16) us16 Pw[4][16 * 72];

  const int t = threadIdx.x, wv = t >> 6, lane = t & 63;
  const int lane15 = lane & 15, quad = lane >> 4;
  const int i0w = tile * 64 + wv * 16;
  const bool active = i0w < dlen;  // dlen % 16 == 0

  const us16* Qp = Qh + ((size_t)h * Md + doff + (active ? i0w : 0)) * 64;
  const us16* Kp = Kh + ((size_t)h * Ms + soff) * 64;
  const us16* Vtp = Vt + ((size_t)h * 64) * Ms + soff;

  short8 af0 = *(const short8*)(Qp + (size_t)lane15 * 64 + quad * 8);
  short8 af1 = *(const short8*)(Qp + (size_t)lane15 * 64 + 32 + quad * 8);

  floatx4 oa[4];
#pragma unroll
  for (int nt = 0; nt < 4; ++nt) oa[nt] = (floatx4){0.f, 0.f, 0.f, 0.f};
  float m_r[4] = {-3.0e38f, -3.0e38f, -3.0e38f, -3.0e38f};
  float l_r[4] = {0.f, 0.f, 0.f, 0.f};

  for (int j0 = 0; j0 < slen; j0 += 64) {
#pragma unroll
    for (int p = 0; p < 2; ++p) {
      int row = wv * 16 + p * 8 + (lane >> 3);
      int sl = lane & 7;
      int kg = sl ^ SW3(row);
      gld16(Kp + (size_t)(j0 + row) * 64 + kg * 8, Ks + (wv * 16 + p * 8) * 64);
      gld16(Vtp + (size_t)row * Ms + j0 + kg * 8, Vts + (wv * 16 + p * 8) * 64);
    }
    __syncthreads();

    if (active) {
      floatx4 s[4];
#pragma unroll
      for (int jt = 0; jt < 4; ++jt) {
        int j = jt * 16 + lane15;
        short8 b0 = *(const short8*)(Ks + j * 64 + ((quad ^ SW3(j)) * 8));
        short8 b1 = *(const short8*)(Ks + j * 64 + (((4 + quad) ^ SW3(j)) * 8));
        floatx4 a = (floatx4){0.f, 0.f, 0.f, 0.f};
        a = __builtin_amdgcn_mfma_f32_16x16x32_bf16(af0, b0, a, 0, 0, 0);
        a = __builtin_amdgcn_mfma_f32_16x16x32_bf16(af1, b1, a, 0, 0, 0);
        s[jt] = a;
      }
      float mx[4] = {-3.0e38f, -3.0e38f, -3.0e38f, -3.0e38f};
#pragma unroll
      for (int jt = 0; jt < 4; ++jt) {
        bool valid = (j0 + jt * 16 + lane15) < slen;
#pragma unroll
        for (int r = 0; r < 4; ++r) {
          float v = valid ? s[jt][r] * 0.125f : -3.0e38f;
          s[jt][r] = v;
          mx[r] = fmaxf(mx[r], v);
        }
      }
#pragma unroll
      for (int r = 0; r < 4; ++r) {
        mx[r] = fmaxf(mx[r], __shfl_xor(mx[r], 1));
        mx[r] = fmaxf(mx[r], __shfl_xor(mx[r], 2));
        mx[r] = fmaxf(mx[r], __shfl_xor(mx[r], 4));
        mx[r] = fmaxf(mx[r], __shfl_xor(mx[r], 8));
      }
      float al[4], sum[4];
#pragma unroll
      for (int r = 0; r < 4; ++r) {
        float mn = fmaxf(m_r[r], mx[r]);
        al[r] = __expf(m_r[r] - mn);
        m_r[r] = mn;
        sum[r] = 0.f;
      }
#pragma unroll
      for (int jt = 0; jt < 4; ++jt)
#pragma unroll
        for (int r = 0; r < 4; ++r) {
          float e = __expf(s[jt][r] - m_r[r]);
          sum[r] += e;
          Pw[wv][(quad * 4 + r) * 72 + jt * 16 + lane15] = f2bf(e);
        }
#pragma unroll
      for (int r = 0; r < 4; ++r) {
        sum[r] += __shfl_xor(sum[r], 1);
        sum[r] += __shfl_xor(sum[r], 2);
        sum[r] += __shfl_xor(sum[r], 4);
        sum[r] += __shfl_xor(sum[r], 8);
        l_r[r] = l_r[r] * al[r] + sum[r];
      }
#pragma unroll
      for (int nt = 0; nt < 4; ++nt)
#pragma unroll
        for (int r = 0; r < 4; ++r) oa[nt][r] *= al[r];
      short8 pa0 = *(const short8*)(&Pw[wv][lane15 * 72 + quad * 8]);
      short8 pa1 = *(const short8*)(&Pw[wv][lane15 * 72 + 32 + quad * 8]);
#pragma unroll
      for (int nt = 0; nt < 4; ++nt) {
        int d = nt * 16 + lane15;
        short8 v0 = *(const short8*)(Vts + d * 64 + ((quad ^ SW3(d)) * 8));
        short8 v1 = *(const short8*)(Vts + d * 64 + (((4 + quad) ^ SW3(d)) * 8));
        oa[nt] = __builtin_amdgcn_mfma_f32_16x16x32_bf16(pa0, v0, oa[nt], 0, 0, 0);
        oa[nt] = __builtin_amdgcn_mfma_f32_16x16x32_bf16(pa1, v1, oa[nt], 0, 0, 0);
      }
    }
    __syncthreads();
  }

  if (active) {
    float linv[4];
#pragma unroll
    for (int r = 0; r < 4; ++r) linv[r] = 1.f / l_r[r];
#pragma unroll
    for (int r = 0; r < 4; ++r) {
      int i = quad * 4 + r;
      us16* orow = O + (size_t)(doff + i0w + i) * H_DIM + h;
#pragma unroll
      for (int nt = 0; nt < 4; ++nt) {
        int d = nt * 16 + lane15;
        orow[d * 8] = f2bf(oa[nt][r] * linv[r]);
      }
    }
  }
}

// ---------------------------------------------------------------------------
// BN apply: optional ReLU / residual; out_bf selects bf16 vs fp32 output.
// ---------------------------------------------------------------------------
__global__ __launch_bounds__(256) void bn_apply(
    const float* __restrict__ X, const float* __restrict__ stats,
    const float* __restrict__ g, const float* __restrict__ be,
    const float* __restrict__ resid, void* __restrict__ Y,
    int M, float invM, int relu, int out_bf) {
  const size_t total = (size_t)M * H_DIM;
  for (size_t i = (size_t)blockIdx.x * 256 + threadIdx.x; i < total;
       i += (size_t)gridDim.x * 256) {
    int c = (int)(i & (H_DIM - 1));
    float mean = stats[c] * invM;
    float var = fmaf(-mean, mean, stats[H_DIM + c] * invM);
    float x = X[i];
    float y = (x - mean) * rsqrtf(var + 1e-5f) * g[c] + be[c];
    if (relu) y = fmaxf(y, 0.f);
    if (resid) y += resid[i];
    if (out_bf) ((us16*)Y)[i] = f2bf(y);
    else ((float*)Y)[i] = y;
  }
}

// ---------------------------------------------------------------------------
extern "C" void kernel_launch(void* const* d_in, const int* in_sizes, int n_in,
                              void* d_out, int out_size, void* d_ws, size_t ws_size,
                              hipStream_t stream) {
  const float* src_h = (const float*)d_in[0];
  const float* dst_h = (const float*)d_in[1];
  const int* s_lens  = (const int*)d_in[2];
  const int* d_lens  = (const int*)d_in[3];
  const float* Wq = (const float*)d_in[4];  const float* bq = (const float*)d_in[5];
  const float* Wk = (const float*)d_in[6];  const float* bk = (const float*)d_in[7];
  const float* Wv = (const float*)d_in[8];  const float* bv = (const float*)d_in[9];
  const float* Wm = (const float*)d_in[10]; const float* bm = (const float*)d_in[11];
  const float* W1 = (const float*)d_in[12]; const float* b1 = (const float*)d_in[13];
  const float* g1 = (const float*)d_in[14]; const float* be1 = (const float*)d_in[15];
  const float* W2 = (const float*)d_in[16]; const float* b2 = (const float*)d_in[17];
  const float* g2 = (const float*)d_in[18]; const float* be2 = (const float*)d_in[19];

  const int total_src = in_sizes[0] / H_DIM;  // 7232
  const int total_dst = in_sizes[1] / H_DIM;  // 6016 = 47*128

  // ---- workspace layout (byte offsets); peak ~50.5 MB ----
  char* ws = (char*)d_ws;
  us16* src_bf = (us16*)(ws + 0);                    //  7,405,568
  us16* dst_bf = (us16*)(ws + 7405568);              //  6,160,384
  us16* wbf    = (us16*)(ws + 13565952);             //  3,145,728 used
  float* b1p   = (float*)(ws + 16711680);            //  2,048
  us16* Qh     = (us16*)(ws + 17235968);             //  6,160,384
  us16* Kh     = (us16*)(ws + 23396352);             //  7,405,568
  us16* Vt     = (us16*)(ws + 30801920);             //  7,405,568
  us16* Ob     = (us16*)(ws + 38207488);             //  6,160,384
  us16* X1bf   = (us16*)(ws + 44367872);             //  6,160,384
  float* st    = (float*)(ws + 50528256);            //  8,192
  float* X1    = (float*)(ws + 17235968);            // aliases Qh+Kh (dead)
  float* X2    = (float*)(ws + 30801920);            // aliases Vt+Ob (dead)
  float* st1 = st, *st2 = st + 1024;

  us16* Wqb = wbf;                 // 262144 elems
  us16* Wkv = wbf + 262144;        // 524288 (Wk rows then Wv rows)
  us16* Wf  = wbf + 786432;        // 524288 ([W1a | Wc] rows of 1024)
  us16* W2b = wbf + 1310720;       // 262144

  const dim3 blk256(256);

  // 1: casts + weight composites + BN-stat zero
  prep_all<<<dim3(2114), blk256, 0, stream>>>(
      src_h, dst_h, Wq, Wk, Wv, W1, W2, Wm, b1, bm,
      src_bf, dst_bf, Wqb, Wkv, Wf, W2b, b1p, st,
      total_src * H_DIM, total_dst * H_DIM);

  // 2: Q + fused K/V projections (XCD-striped 1D grid: 192 + 512 = 704)
  gemm_qkv<<<dim3(704), blk256, 0, stream>>>(
      dst_bf, src_bf, Wqb, Wkv, bq, bk, bv, Qh, Kh, Vt, total_dst, total_src);

  // 3: attention -> Ob (bf16 [M,512])
  attn_v6<<<dim3(NBATCH, N_HEADS, 8), blk256, 0, stream>>>(
      Qh, Kh, Vt, d_lens, s_lens, Ob, total_dst, total_src);

  // 4: FFN1 (merge folded in): [dst_bf | Ob] @ Wf^T + b1p -> X1 + BN1 stats
  gemm_ffn<<<dim3(192), blk256, 0, stream>>>(
      dst_bf, Ob, Wf, b1p, X1, st1, total_dst, 1024);

  // 5: BN1 + ReLU -> X1bf
  bn_apply<<<dim3(512), blk256, 0, stream>>>(X1, st1, g1, be1, nullptr, X1bf,
                                             total_dst, 1.f / (float)total_dst, 1, 1);

  // 6: FFN2 -> X2 + BN2 stats
  gemm_ffn<<<dim3(192), blk256, 0, stream>>>(
      X1bf, X1bf, W2b, b2, X2, st2, total_dst, 512);

  // 7: BN2 + residual -> d_out
  bn_apply<<<dim3(512), blk256, 0, stream>>>(X2, st2, g2, be2, dst_h, d_out,
                                             total_dst, 1.f / (float)total_dst, 0, 0);
}